// Round 7
// baseline (359.996 us; speedup 1.0000x reference)
//
#include <hip/hip_runtime.h>

#define NDIM 256
#define INNER 512
#define NH 8
#define ND 64
#define NS 32
#define NB 8
#define NP 30208   // padded node count

typedef __attribute__((ext_vector_type(8))) short short8;   // 8 bf16 = 4 VGPR
typedef __attribute__((ext_vector_type(4))) float f32x4;

static __device__ __forceinline__ short f2bf(float f) {
  unsigned u = __float_as_uint(f);
  unsigned r = (u + 0x7fffu + ((u >> 16) & 1u)) >> 16;
  return (short)r;
}
static __device__ __forceinline__ float bf2f(short s) {
  return __uint_as_float(((unsigned)(unsigned short)s) << 16);
}

// async global->LDS, 16 B per lane; dest = uniform lds base + lane*16
static __device__ __forceinline__ void gl_lds16(const void* g, void* l) {
  __builtin_amdgcn_global_load_lds(
      (const __attribute__((address_space(1))) unsigned int*)g,
      (__attribute__((address_space(3))) unsigned int*)l, 16, 0, 0);
}

// ---------------------------------------------------------------------------
// k_pre: merged preprocessing.
//  blocks [0,7500): x fp32 -> Xh/Xl bf16 hi/lo
//  blocks [7500,8270): Bt1 [768][256] hi/lo + bcomb
//  blocks [8270,8388): seg boundaries (seg pre-memset to 0x7f7f7f7f)
// ---------------------------------------------------------------------------
__global__ __launch_bounds__(256) void k_pre(
    const float* __restrict__ x, short* __restrict__ Xh, short* __restrict__ Xl,
    const float* __restrict__ Wfx, const float* __restrict__ Wx,
    const float* __restrict__ bx, const float* __restrict__ Wsl,
    const float* __restrict__ bsl,
    short* __restrict__ Bt1h, short* __restrict__ Bt1l,
    float* __restrict__ bcomb,
    const int* __restrict__ batch, int* __restrict__ seg, int N)
{
  const int bid = blockIdx.x;
  if (bid < 7500) {                    // ---- xsplit
    int id = bid * 256 + threadIdx.x;
    if (id >= N * 64) return;
    float4 v = *(const float4*)&x[(size_t)id * 4];
    short h0 = f2bf(v.x), h1 = f2bf(v.y), h2 = f2bf(v.z), h3 = f2bf(v.w);
    short4 hv = make_short4(h0, h1, h2, h3);
    short4 lv = make_short4(f2bf(v.x - bf2f(h0)), f2bf(v.y - bf2f(h1)),
                            f2bf(v.z - bf2f(h2)), f2bf(v.w - bf2f(h3)));
    *(short4*)&Xh[(size_t)id * 4] = hv;
    *(short4*)&Xl[(size_t)id * 4] = lv;
  } else if (bid < 8270) {             // ---- weight prep
    int id = (bid - 7500) * 256 + threadIdx.x;
    if (id < 131072) {
      int k = id >> 9, n = id & 511;
      float v = Wfx[k * 512 + n];
      short hi = f2bf(v); short lo = f2bf(v - bf2f(hi));
      Bt1h[n * 256 + k] = hi; Bt1l[n * 256 + k] = lo;
    } else if (id < 196608) {
      int e = id - 131072;
      int c = e & 255, k = e >> 8;
      int h = c >> 5, s = c & 31;
      float acc = 0.f;
      #pragma unroll 8
      for (int d = 0; d < 64; d++) acc += Wx[k * 512 + h * 64 + d] * Wsl[d * 32 + s];
      short hi = f2bf(acc); short lo = f2bf(acc - bf2f(hi));
      Bt1h[(512 + c) * 256 + k] = hi; Bt1l[(512 + c) * 256 + k] = lo;
    } else if (id < 196864) {
      int c = id - 196608;
      int h = c >> 5, s = c & 31;
      float acc = bsl[s];
      #pragma unroll 8
      for (int d = 0; d < 64; d++) acc += bx[h * 64 + d] * Wsl[d * 32 + s];
      bcomb[c] = acc;
    }
  } else {                             // ---- segs
    int i = (bid - 8270) * 256 + threadIdx.x;
    if (i >= N) return;
    int b = batch[i];
    int p = (i == 0) ? -1 : batch[i - 1];
    if (i == 0) seg[0] = 0;
    for (int v = p + 1; v <= b; v++)
      if (v >= 1) atomicMin(&seg[v], i);
    if (i == N - 1)
      for (int v = b + 1; v <= 8; v++) atomicMin(&seg[v], N);
  }
}

// ---------------------------------------------------------------------------
// k_fxw: C[N,768] = x @ Bt1^T, split-3 bf16 MFMA. 512 threads = 8 waves
// (2 m x 4 n), tile BM=128 x BN=256, 3 ct-tiles (0,1 = fx; 2 = w).
// DMA staging; LDS operand layout [rowgrp16][kchunk8][row16] (lane*16B dest).
// ---------------------------------------------------------------------------
__global__ __launch_bounds__(512) void k_fxw(
    const short* __restrict__ Xh, const short* __restrict__ Xl,
    const short* __restrict__ Bt1h, const short* __restrict__ Bt1l,
    const float* __restrict__ bfx, const float* __restrict__ bcomb,
    const float* __restrict__ gtemp,
    short* __restrict__ fxTh, short* __restrict__ fxTl,
    short* __restrict__ wh_out, short* __restrict__ wl_out,
    int N, int ntiles)
{
  __shared__ __align__(16) short smem[24576];   // 48 KB
  short* AhL = &smem[0];          // 4096 shorts (128x32)
  short* AlL = &smem[4096];
  short* BhL = &smem[8192];       // 8192 shorts (256x32)
  short* BlL = &smem[16384];

  const int lid = blockIdx.x;
  const int xcd = lid & 7;
  const int idx = lid >> 3;
  const int ct  = idx % 3;
  const int rowt = xcd + 8 * (idx / 3);
  if (rowt >= ntiles) return;
  const int row0 = rowt * 128;
  const int tid = threadIdx.x;
  const int lane = tid & 63, l15 = lane & 15, quad = lane >> 4;
  const int wvi = tid >> 6;            // 0..7
  const int wm = wvi & 1, wn = wvi >> 1;
  const int cb = ct * 256;             // col base in [0,768)
  const int srow = lane & 15, schunk = lane >> 4;

  f32x4 acc[4][4];
  #pragma unroll
  for (int i = 0; i < 4; i++)
    #pragma unroll
    for (int j = 0; j < 4; j++) acc[i][j] = (f32x4){0.f, 0.f, 0.f, 0.f};

  for (int kt = 0; kt < 8; kt++) {       // K=256, BK=32
    {
      int g = wvi;                       // A rowgroup (8 groups x 16 rows)
      int gr = row0 + g * 16 + srow;
      if (gr > N - 1) gr = N - 1;        // clamp (finite garbage, masked later)
      size_t aoff = (size_t)gr * 256 + kt * 32 + schunk * 8;
      gl_lds16(Xh + aoff, AhL + g * 512);
      gl_lds16(Xl + aoff, AlL + g * 512);
    }
    #pragma unroll
    for (int t = 0; t < 2; t++) {        // B rowgroups (16 groups x 16 rows)
      int g2 = wvi + t * 8;
      int br = cb + g2 * 16 + srow;
      size_t boff = (size_t)br * 256 + kt * 32 + schunk * 8;
      gl_lds16(Bt1h + boff, BhL + g2 * 512);
      gl_lds16(Bt1l + boff, BlL + g2 * 512);
    }
    __syncthreads();

    short8 ah[4], al[4];
    #pragma unroll
    for (int mt = 0; mt < 4; mt++) {
      int rg = wm * 4 + mt;
      ah[mt] = *(const short8*)&AhL[rg * 512 + quad * 128 + l15 * 8];
      al[mt] = *(const short8*)&AlL[rg * 512 + quad * 128 + l15 * 8];
    }
    #pragma unroll
    for (int nt = 0; nt < 4; nt++) {
      int rg = wn * 4 + nt;
      short8 bh = *(const short8*)&BhL[rg * 512 + quad * 128 + l15 * 8];
      short8 bl = *(const short8*)&BlL[rg * 512 + quad * 128 + l15 * 8];
      #pragma unroll
      for (int mt = 0; mt < 4; mt++) {
        acc[mt][nt] = __builtin_amdgcn_mfma_f32_16x16x32_bf16(ah[mt], bh, acc[mt][nt], 0, 0, 0);
        acc[mt][nt] = __builtin_amdgcn_mfma_f32_16x16x32_bf16(ah[mt], bl, acc[mt][nt], 0, 0, 0);
        acc[mt][nt] = __builtin_amdgcn_mfma_f32_16x16x32_bf16(al[mt], bh, acc[mt][nt], 0, 0, 0);
      }
    }
    __syncthreads();
  }

  if (ct < 2) {
    // fx: LDS transpose (half=128 cols at a time), store fxT hi/lo
    short (*T)[136] = (short(*)[136])&smem[0];   // 128 x 136 shorts
    #pragma unroll
    for (int half = 0; half < 2; half++) {
      #pragma unroll
      for (int pass = 0; pass < 2; pass++) {
        __syncthreads();
        if ((wn >> 1) == half) {
          #pragma unroll
          for (int nt = 0; nt < 4; nt++) {
            int cl = (wn & 1) * 64 + nt * 16 + l15;       // 0..127
            float bias = bfx[cb + half * 128 + cl];
            #pragma unroll
            for (int mt = 0; mt < 4; mt++) {
              short4 sv;
              #pragma unroll
              for (int r = 0; r < 4; r++) {
                float v = acc[mt][nt][r] + bias;
                short hi2 = f2bf(v);
                ((short*)&sv)[r] = pass ? f2bf(v - bf2f(hi2)) : hi2;
              }
              *(short4*)&T[cl][wm * 64 + mt * 16 + quad * 4] = sv;
            }
          }
        }
        __syncthreads();
        short* dst = pass ? fxTl : fxTh;
        #pragma unroll
        for (int t = 0; t < 4; t++) {
          int idx2 = tid + t * 512;                 // 2048 int4 chunks
          int row = idx2 >> 4, kc = (idx2 & 15) * 8;
          *(int4*)&dst[(size_t)(cb + half * 128 + row) * NP + row0 + kc] =
              *(const int4*)&T[row][kc];
        }
      }
    }
  } else {
    // w: logits -> tempered softmax per 32-col group
    #pragma unroll
    for (int g = 0; g < 2; g++) {
      int lcbase = wn * 64 + g * 32;         // 0..224, 32-aligned
      int h = lcbase >> 5;
      float inv_t = 1.0f / gtemp[h];
      int lc0 = lcbase + l15, lc1 = lcbase + 16 + l15;
      float b0 = bcomb[lc0], b1 = bcomb[lc1];
      #pragma unroll
      for (int mt = 0; mt < 4; mt++) {
        #pragma unroll
        for (int r = 0; r < 4; r++) {
          float s0 = (acc[mt][2 * g + 0][r] + b0) * inv_t;
          float s1 = (acc[mt][2 * g + 1][r] + b1) * inv_t;
          float m = fmaxf(s0, s1);
          #pragma unroll
          for (int off = 1; off < 16; off <<= 1) m = fmaxf(m, __shfl_xor(m, off, 16));
          float e0 = __expf(s0 - m), e1 = __expf(s1 - m);
          float sum = e0 + e1;
          #pragma unroll
          for (int off = 1; off < 16; off <<= 1) sum += __shfl_xor(sum, off, 16);
          float inv = 1.0f / sum;
          int row = row0 + wm * 64 + mt * 16 + quad * 4 + r;
          if (row < N) {
            float w0v = e0 * inv, w1v = e1 * inv;
            size_t base = (size_t)row * (NH * NS);
            short h0 = f2bf(w0v), h1 = f2bf(w1v);
            wh_out[base + lc0] = h0; wl_out[base + lc0] = f2bf(w0v - bf2f(h0));
            wh_out[base + lc1] = h1; wl_out[base + lc1] = f2bf(w1v - bf2f(h1));
          }
        }
      }
    }
  }
}

// ---------------------------------------------------------------------------
// k_scat: slice_token[b,h,s,d] = sum_n w[n,hs]*fx[n,hd], split-3 MFMA over
// K=nodes (unchanged from round 6 — verified).
// ---------------------------------------------------------------------------
__global__ __launch_bounds__(256) void k_scat(
    const short* __restrict__ wh, const short* __restrict__ wl,
    const short* __restrict__ fxTh, const short* __restrict__ fxTl,
    const int* __restrict__ seg,
    float* __restrict__ stok, float* __restrict__ snorm, int N)
{
  __shared__ short wth[32][136];
  __shared__ short wtl[32][136];
  __shared__ short fh[64][136];
  __shared__ short fl[64][136];
  __shared__ float ln[32];

  const int h = blockIdx.y;
  const int n0 = blockIdx.x * 512;
  const int tid = threadIdx.x;
  const int lane = tid & 63, l15 = lane & 15, quad = lane >> 4;
  const int wv = tid >> 6;
  const int nend = min(n0 + 512, N);

  f32x4 acc0 = (f32x4){0.f, 0.f, 0.f, 0.f};
  f32x4 acc1 = (f32x4){0.f, 0.f, 0.f, 0.f};

  for (int b = 0; b < NB; b++) {
    int lo = max(seg[b], n0), hi = min(seg[b + 1], nend);
    if (lo >= hi) continue;
    if (tid < 32) ln[tid] = 0.f;
    int c0lo = (lo - n0) & ~127;
    int c0hi = hi - n0;
    for (int c0 = c0lo; c0 < c0hi; c0 += 128) {
      __syncthreads();
      #pragma unroll
      for (int t = 0; t < 2; t++) {
        int idx2 = tid + t * 256;
        int row = idx2 >> 2;
        int sc  = (idx2 & 3) * 8;
        int ng = n0 + c0 + row;
        short8 vh = (short8){0,0,0,0,0,0,0,0};
        short8 vl = (short8){0,0,0,0,0,0,0,0};
        if (ng >= lo && ng < hi) {
          size_t src = (size_t)ng * 256 + h * 32 + sc;
          vh = *(const short8*)&wh[src];
          vl = *(const short8*)&wl[src];
        }
        #pragma unroll
        for (int j = 0; j < 8; j++) {
          wth[sc + j][row] = vh[j];
          wtl[sc + j][row] = vl[j];
        }
      }
      #pragma unroll
      for (int t = 0; t < 4; t++) {
        int idx2 = tid + t * 256;
        int row = idx2 >> 4, kc = (idx2 & 15) * 8;
        size_t src = (size_t)(h * 64 + row) * NP + n0 + c0 + kc;
        *(int4*)&fh[row][kc] = *(const int4*)&fxTh[src];
        *(int4*)&fl[row][kc] = *(const int4*)&fxTl[src];
      }
      __syncthreads();

      {
        int s = tid >> 3, g = tid & 7;
        float sum = 0.f;
        #pragma unroll
        for (int i2 = 0; i2 < 16; i2++) {
          int nl = g * 16 + i2;
          sum += bf2f(wth[s][nl]) + bf2f(wtl[s][nl]);
        }
        atomicAdd(&ln[s], sum);
      }

      for (int k0 = 0; k0 < 128; k0 += 32) {
        int gbase = n0 + c0 + k0;
        if (gbase + 32 <= lo || gbase >= hi) continue;
        short8 a0h = *(const short8*)&wth[l15][k0 + quad * 8];
        short8 a0l = *(const short8*)&wtl[l15][k0 + quad * 8];
        short8 a1h = *(const short8*)&wth[16 + l15][k0 + quad * 8];
        short8 a1l = *(const short8*)&wtl[16 + l15][k0 + quad * 8];
        short8 bh = *(const short8*)&fh[wv * 16 + l15][k0 + quad * 8];
        short8 bl = *(const short8*)&fl[wv * 16 + l15][k0 + quad * 8];
        acc0 = __builtin_amdgcn_mfma_f32_16x16x32_bf16(a0h, bh, acc0, 0, 0, 0);
        acc0 = __builtin_amdgcn_mfma_f32_16x16x32_bf16(a0h, bl, acc0, 0, 0, 0);
        acc0 = __builtin_amdgcn_mfma_f32_16x16x32_bf16(a0l, bh, acc0, 0, 0, 0);
        acc1 = __builtin_amdgcn_mfma_f32_16x16x32_bf16(a1h, bh, acc1, 0, 0, 0);
        acc1 = __builtin_amdgcn_mfma_f32_16x16x32_bf16(a1h, bl, acc1, 0, 0, 0);
        acc1 = __builtin_amdgcn_mfma_f32_16x16x32_bf16(a1l, bh, acc1, 0, 0, 0);
      }
    }
    __syncthreads();
    size_t base = ((size_t)b * NH + h) * NS;
    #pragma unroll
    for (int r = 0; r < 4; r++) {
      atomicAdd(&stok[(base + quad * 4 + r) * ND + wv * 16 + l15], acc0[r]);
      atomicAdd(&stok[(base + 16 + quad * 4 + r) * ND + wv * 16 + l15], acc1[r]);
    }
    if (tid < 32) atomicAdd(&snorm[base + tid], ln[tid]);
    acc0 = (f32x4){0.f, 0.f, 0.f, 0.f};
    acc1 = (f32x4){0.f, 0.f, 0.f, 0.f};
    __syncthreads();
  }
}

// ---------------------------------------------------------------------------
// k_attn: per (b,h) attention + P = out_tok @ Wout_h, store P^T bf16 hi/lo.
// ---------------------------------------------------------------------------
__global__ __launch_bounds__(256) void k_attn(
    const float* __restrict__ stok, const float* __restrict__ snorm,
    const float* __restrict__ Wq, const float* __restrict__ Wk,
    const float* __restrict__ Wv, const float* __restrict__ Wout,
    short* __restrict__ PTh, short* __restrict__ PTl)
{
  __shared__ float st[32][65];
  __shared__ float qs[32][65];
  __shared__ float ks[32][65];
  __shared__ float vs[32][65];
  __shared__ float at[32][33];
  __shared__ float ot[32][65];
  const int bh = blockIdx.x;
  const int b = bh >> 3, h = bh & 7;
  const int tid = threadIdx.x;

  for (int i = tid; i < 2048; i += 256) {
    int ss = i >> 6;
    float nrm = snorm[(size_t)bh * NS + ss] + 1e-5f;
    st[ss][i & 63] = stok[(size_t)bh * 2048 + i] / nrm;
  }
  __syncthreads();

  const int e = tid & 63, sgp = tid >> 6;
  for (int ii = 0; ii < 8; ii++) {
    int ss = sgp * 8 + ii;
    float aq = 0.f, ak = 0.f, av = 0.f;
    #pragma unroll 8
    for (int dd = 0; dd < 64; dd++) {
      float sv = st[ss][dd];
      aq += sv * Wq[dd * 64 + e];
      ak += sv * Wk[dd * 64 + e];
      av += sv * Wv[dd * 64 + e];
    }
    qs[ss][e] = aq; ks[ss][e] = ak; vs[ss][e] = av;
  }
  __syncthreads();

  const float scale = 0.125f;
  for (int i = tid; i < 1024; i += 256) {
    int si = i >> 5, tj = i & 31;
    float a = 0.f;
    #pragma unroll 8
    for (int ee = 0; ee < 64; ee++) a += qs[si][ee] * ks[tj][ee];
    at[si][tj] = a * scale;
  }
  __syncthreads();

  if (tid < 32) {
    float m = -1e30f;
    for (int j = 0; j < 32; j++) m = fmaxf(m, at[tid][j]);
    float sum = 0.f;
    for (int j = 0; j < 32; j++) { float ev = __expf(at[tid][j] - m); at[tid][j] = ev; sum += ev; }
    float inv = 1.f / sum;
    for (int j = 0; j < 32; j++) at[tid][j] *= inv;
  }
  __syncthreads();

  for (int ii = 0; ii < 8; ii++) {
    int ss = sgp * 8 + ii;
    float a = 0.f;
    #pragma unroll 8
    for (int tj = 0; tj < 32; tj++) a += at[ss][tj] * vs[tj][e];
    ot[ss][e] = a;
  }
  __syncthreads();

  const int s_p = tid >> 3;
  const int c0 = (tid & 7) * 32;
  float pacc[32];
  #pragma unroll
  for (int q = 0; q < 32; q++) pacc[q] = 0.f;
  for (int dd = 0; dd < 64; dd++) {
    float o = ot[s_p][dd];
    const float4* wr = (const float4*)&Wout[(size_t)(h * 64 + dd) * NDIM + c0];
    #pragma unroll
    for (int q = 0; q < 8; q++) {
      float4 v = wr[q];
      pacc[4 * q + 0] += o * v.x;
      pacc[4 * q + 1] += o * v.y;
      pacc[4 * q + 2] += o * v.z;
      pacc[4 * q + 3] += o * v.w;
    }
  }
  #pragma unroll
  for (int q = 0; q < 32; q++) {
    int c = c0 + q;
    float val = pacc[q];
    short hi = f2bf(val);
    size_t dst = ((size_t)b * NDIM + c) * 256 + h * 32 + s_p;
    PTh[dst] = hi;
    PTl[dst] = f2bf(val - bf2f(hi));
  }
}

// ---------------------------------------------------------------------------
// k_outw: out[n,c] = sum_{hs} w[n,hs] * PT[batch[n]][c][hs] + bout[c].
// 512 threads = 8 waves, tile 128 x 256 (full width). DMA staging for the
// common full-segment case; masked VGPR path at segment boundaries.
// ---------------------------------------------------------------------------
__global__ __launch_bounds__(512) void k_outw(
    const short* __restrict__ wh, const short* __restrict__ wl,
    const short* __restrict__ PTh, const short* __restrict__ PTl,
    const int* __restrict__ batch, const float* __restrict__ bout,
    float* __restrict__ out, int N, int ntiles)
{
  __shared__ __align__(16) short smem[24576];   // 48 KB
  short* AhL = &smem[0];
  short* AlL = &smem[4096];
  short* BhL = &smem[8192];
  short* BlL = &smem[16384];
  __shared__ int b_sh[128];

  const int lid = blockIdx.x;
  const int xcd = lid & 7;
  const int rowt = xcd + 8 * (lid >> 3);
  if (rowt >= ntiles) return;
  const int row0 = rowt * 128;
  const int tid = threadIdx.x;
  const int lane = tid & 63, l15 = lane & 15, quad = lane >> 4;
  const int wvi = tid >> 6, wm = wvi & 1, wn = wvi >> 1;
  const int srow = lane & 15, schunk = lane >> 4;
  const int cnt = min(128, N - row0);

  if (tid < 128) b_sh[tid] = (tid < cnt) ? batch[row0 + tid] : -1;
  __syncthreads();

  f32x4 acc[4][4];
  #pragma unroll
  for (int i = 0; i < 4; i++)
    #pragma unroll
    for (int j = 0; j < 4; j++) acc[i][j] = (f32x4){0.f, 0.f, 0.f, 0.f};

  int i0 = 0;
  while (i0 < cnt) {
    int b = b_sh[i0];
    int j = i0;
    while (j < cnt && b_sh[j] == b) j++;
    const bool fullseg = (i0 == 0) && (j == cnt) && (cnt == 128);

    for (int kt = 0; kt < 8; kt++) {
      if (fullseg) {
        int g = wvi;
        int gr = row0 + g * 16 + srow;
        size_t aoff = (size_t)gr * 256 + kt * 32 + schunk * 8;
        gl_lds16(wh + aoff, AhL + g * 512);
        gl_lds16(wl + aoff, AlL + g * 512);
      } else {
        int row = tid >> 2, kc8 = tid & 3;     // 512 chunks exactly
        short8 vh = (short8){0,0,0,0,0,0,0,0};
        short8 vl = (short8){0,0,0,0,0,0,0,0};
        if (row >= i0 && row < j) {
          size_t src = (size_t)(row0 + row) * 256 + kt * 32 + kc8 * 8;
          vh = *(const short8*)&wh[src];
          vl = *(const short8*)&wl[src];
        }
        int dst = (row >> 4) * 512 + kc8 * 128 + (row & 15) * 8;
        *(short8*)&AhL[dst] = vh;
        *(short8*)&AlL[dst] = vl;
      }
      #pragma unroll
      for (int t = 0; t < 2; t++) {
        int g2 = wvi + t * 8;
        int br = g2 * 16 + srow;
        size_t boff = ((size_t)b * NDIM + br) * 256 + kt * 32 + schunk * 8;
        gl_lds16(PTh + boff, BhL + g2 * 512);
        gl_lds16(PTl + boff, BlL + g2 * 512);
      }
      __syncthreads();

      short8 ah[4], al[4];
      #pragma unroll
      for (int mt = 0; mt < 4; mt++) {
        int rg = wm * 4 + mt;
        ah[mt] = *(const short8*)&AhL[rg * 512 + quad * 128 + l15 * 8];
        al[mt] = *(const short8*)&AlL[rg * 512 + quad * 128 + l15 * 8];
      }
      #pragma unroll
      for (int nt = 0; nt < 4; nt++) {
        int rg = wn * 4 + nt;
        short8 bh = *(const short8*)&BhL[rg * 512 + quad * 128 + l15 * 8];
        short8 bl = *(const short8*)&BlL[rg * 512 + quad * 128 + l15 * 8];
        #pragma unroll
        for (int mt = 0; mt < 4; mt++) {
          acc[mt][nt] = __builtin_amdgcn_mfma_f32_16x16x32_bf16(ah[mt], bh, acc[mt][nt], 0, 0, 0);
          acc[mt][nt] = __builtin_amdgcn_mfma_f32_16x16x32_bf16(ah[mt], bl, acc[mt][nt], 0, 0, 0);
          acc[mt][nt] = __builtin_amdgcn_mfma_f32_16x16x32_bf16(al[mt], bh, acc[mt][nt], 0, 0, 0);
        }
      }
      __syncthreads();
    }
    i0 = j;
  }

  #pragma unroll
  for (int nt = 0; nt < 4; nt++) {
    int c = wn * 64 + nt * 16 + l15;
    float bias = bout[c];
    #pragma unroll
    for (int mt = 0; mt < 4; mt++)
      #pragma unroll
      for (int r = 0; r < 4; r++) {
        int row = row0 + wm * 64 + mt * 16 + quad * 4 + r;
        if (row < N) out[(size_t)row * NDIM + c] = acc[mt][nt][r] + bias;
      }
  }
}

// ---------------------------------------------------------------------------
extern "C" void kernel_launch(void* const* d_in, const int* in_sizes, int n_in,
                              void* d_out, int out_size, void* d_ws, size_t ws_size,
                              hipStream_t stream) {
  const float* x      = (const float*)d_in[0];
  const int*   batch  = (const int*)d_in[1];
  const float* Wfx    = (const float*)d_in[2];
  const float* bfx    = (const float*)d_in[3];
  const float* Wx     = (const float*)d_in[4];
  const float* bx     = (const float*)d_in[5];
  const float* Wsl    = (const float*)d_in[6];
  const float* bsl    = (const float*)d_in[7];
  const float* gtemp  = (const float*)d_in[8];
  const float* Wq     = (const float*)d_in[9];
  const float* Wk     = (const float*)d_in[10];
  const float* Wv     = (const float*)d_in[11];
  const float* Wout   = (const float*)d_in[12];
  const float* bout   = (const float*)d_in[13];
  float* out = (float*)d_out;

  const int N = in_sizes[0] / NDIM;   // 30000

  float* stok  = (float*)d_ws;                     // 131072
  float* snorm = stok + 131072;                    // 2048
  float* bcomb = snorm + 2048;                     // 256
  int*   seg   = (int*)(bcomb + 256);              // 16
  short* Bt1h  = (short*)(seg + 16);               // 196608
  short* Bt1l  = Bt1h + 196608;
  short* Xh    = Bt1l + 196608;                    // N*256
  short* Xl    = Xh + 7680000;
  short* whb   = Xl + 7680000;                     // NP*256
  short* wlb   = whb + (size_t)NP * 256;
  short* fxTh  = wlb + (size_t)NP * 256;           // 512*NP
  short* fxTl  = fxTh + (size_t)512 * NP;
  short* PTh   = fxTl + (size_t)512 * NP;          // 524288
  short* PTl   = PTh + 524288;

  hipMemsetAsync(stok, 0, (size_t)(131072 + 2048) * sizeof(float), stream);
  hipMemsetAsync(seg, 0x7f, 16 * sizeof(int), stream);

  const int xs_blocks = (N * 64 + 255) / 256;      // 7500
  k_pre<<<xs_blocks + 770 + (N + 255) / 256, 256, 0, stream>>>(
      x, Xh, Xl, Wfx, Wx, bx, Wsl, bsl, Bt1h, Bt1l, bcomb, batch, seg, N);

  const int ntiles = (N + 127) / 128;              // 235
  const int qmax = (ntiles + 7) / 8;               // 30
  k_fxw<<<8 * qmax * 3, 512, 0, stream>>>(Xh, Xl, Bt1h, Bt1l, bfx, bcomb, gtemp,
                                          fxTh, fxTl, whb, wlb, N, ntiles);

  dim3 g2((N + 511) / 512, NH);
  k_scat<<<g2, 256, 0, stream>>>(whb, wlb, fxTh, fxTl, seg, stok, snorm, N);

  k_attn<<<NB * NH, 256, 0, stream>>>(stok, snorm, Wq, Wk, Wv, Wout, PTh, PTl);

  k_outw<<<8 * qmax, 512, 0, stream>>>(whb, wlb, PTh, PTl, batch, bout, out, N, ntiles);
}

// Round 8
// 347.643 us; speedup vs baseline: 1.0355x; 1.0355x over previous
//
#include <hip/hip_runtime.h>

#define NDIM 256
#define INNER 512
#define NH 8
#define ND 64
#define NS 32
#define NB 8
#define NP 30208   // padded node count

typedef __attribute__((ext_vector_type(8))) short short8;   // 8 bf16 = 4 VGPR
typedef __attribute__((ext_vector_type(4))) float f32x4;

static __device__ __forceinline__ short f2bf(float f) {
  unsigned u = __float_as_uint(f);
  unsigned r = (u + 0x7fffu + ((u >> 16) & 1u)) >> 16;
  return (short)r;
}
static __device__ __forceinline__ float bf2f(short s) {
  return __uint_as_float(((unsigned)(unsigned short)s) << 16);
}

// async global->LDS, 16 B per lane; dest = uniform lds base + lane*16
static __device__ __forceinline__ void gl_lds16(const void* g, void* l) {
  __builtin_amdgcn_global_load_lds(
      (const __attribute__((address_space(1))) unsigned int*)g,
      (__attribute__((address_space(3))) unsigned int*)l, 16, 0, 0);
}

// ---------------------------------------------------------------------------
// k_pre: merged preprocessing (unchanged from round 7 — verified).
// ---------------------------------------------------------------------------
__global__ __launch_bounds__(256) void k_pre(
    const float* __restrict__ x, short* __restrict__ Xh, short* __restrict__ Xl,
    const float* __restrict__ Wfx, const float* __restrict__ Wx,
    const float* __restrict__ bx, const float* __restrict__ Wsl,
    const float* __restrict__ bsl,
    short* __restrict__ Bt1h, short* __restrict__ Bt1l,
    float* __restrict__ bcomb,
    const int* __restrict__ batch, int* __restrict__ seg, int N)
{
  const int bid = blockIdx.x;
  if (bid < 7500) {                    // ---- xsplit
    int id = bid * 256 + threadIdx.x;
    if (id >= N * 64) return;
    float4 v = *(const float4*)&x[(size_t)id * 4];
    short h0 = f2bf(v.x), h1 = f2bf(v.y), h2 = f2bf(v.z), h3 = f2bf(v.w);
    short4 hv = make_short4(h0, h1, h2, h3);
    short4 lv = make_short4(f2bf(v.x - bf2f(h0)), f2bf(v.y - bf2f(h1)),
                            f2bf(v.z - bf2f(h2)), f2bf(v.w - bf2f(h3)));
    *(short4*)&Xh[(size_t)id * 4] = hv;
    *(short4*)&Xl[(size_t)id * 4] = lv;
  } else if (bid < 8270) {             // ---- weight prep
    int id = (bid - 7500) * 256 + threadIdx.x;
    if (id < 131072) {
      int k = id >> 9, n = id & 511;
      float v = Wfx[k * 512 + n];
      short hi = f2bf(v); short lo = f2bf(v - bf2f(hi));
      Bt1h[n * 256 + k] = hi; Bt1l[n * 256 + k] = lo;
    } else if (id < 196608) {
      int e = id - 131072;
      int c = e & 255, k = e >> 8;
      int h = c >> 5, s = c & 31;
      float acc = 0.f;
      #pragma unroll 8
      for (int d = 0; d < 64; d++) acc += Wx[k * 512 + h * 64 + d] * Wsl[d * 32 + s];
      short hi = f2bf(acc); short lo = f2bf(acc - bf2f(hi));
      Bt1h[(512 + c) * 256 + k] = hi; Bt1l[(512 + c) * 256 + k] = lo;
    } else if (id < 196864) {
      int c = id - 196608;
      int h = c >> 5, s = c & 31;
      float acc = bsl[s];
      #pragma unroll 8
      for (int d = 0; d < 64; d++) acc += bx[h * 64 + d] * Wsl[d * 32 + s];
      bcomb[c] = acc;
    }
  } else {                             // ---- segs
    int i = (bid - 8270) * 256 + threadIdx.x;
    if (i >= N) return;
    int b = batch[i];
    int p = (i == 0) ? -1 : batch[i - 1];
    if (i == 0) seg[0] = 0;
    for (int v = p + 1; v <= b; v++)
      if (v >= 1) atomicMin(&seg[v], i);
    if (i == N - 1)
      for (int v = b + 1; v <= 8; v++) atomicMin(&seg[v], N);
  }
}

// ---------------------------------------------------------------------------
// k_fxw: C[N,768] = x @ Bt1^T, split-3 bf16 MFMA.
// 256 threads = 4 waves (2m x 2n); tile BM=128 x BN=64; 12 ct tiles
// (0..7 = fx, 8..11 = w). acc[4][2] = 32 AGPR -> <=128 total regs ->
// 4 waves/SIMD. DMA staging, LDS op layout [rowgrp16][kchunk8][row16].
// ---------------------------------------------------------------------------
__global__ __launch_bounds__(256) void k_fxw(
    const short* __restrict__ Xh, const short* __restrict__ Xl,
    const short* __restrict__ Bt1h, const short* __restrict__ Bt1l,
    const float* __restrict__ bfx, const float* __restrict__ bcomb,
    const float* __restrict__ gtemp,
    short* __restrict__ fxTh, short* __restrict__ fxTl,
    short* __restrict__ wh_out, short* __restrict__ wl_out,
    int N, int ntiles)
{
  __shared__ __align__(16) short smem[12288];   // 24.6 KB
  short* AhL = &smem[0];          // 4096 shorts (128x32)
  short* AlL = &smem[4096];
  short* BhL = &smem[8192];       // 2048 shorts (64x32)
  short* BlL = &smem[10240];

  const int lid = blockIdx.x;
  const int xcd = lid & 7;
  const int idx = lid >> 3;
  const int ct  = idx % 12;
  const int rowt = xcd + 8 * (idx / 12);
  if (rowt >= ntiles) return;
  const int row0 = rowt * 128;
  const int tid = threadIdx.x;
  const int lane = tid & 63, l15 = lane & 15, quad = lane >> 4;
  const int wvi = tid >> 6;            // 0..3
  const int wm = wvi & 1, wn = wvi >> 1;
  const int cb = ct * 64;              // col base in [0,768)
  const int srow = lane & 15, schunk = lane >> 4;

  f32x4 acc[4][2];
  #pragma unroll
  for (int i = 0; i < 4; i++)
    #pragma unroll
    for (int j = 0; j < 2; j++) acc[i][j] = (f32x4){0.f, 0.f, 0.f, 0.f};

  for (int kt = 0; kt < 8; kt++) {       // K=256, BK=32
    #pragma unroll
    for (int t = 0; t < 2; t++) {        // A rowgroups (8 x 16 rows)
      int g = wvi * 2 + t;
      int gr = row0 + g * 16 + srow;
      if (gr > N - 1) gr = N - 1;        // clamp (garbage masked later)
      size_t aoff = (size_t)gr * 256 + kt * 32 + schunk * 8;
      gl_lds16(Xh + aoff, AhL + g * 512);
      gl_lds16(Xl + aoff, AlL + g * 512);
    }
    {                                     // B rowgroups (4 x 16 rows)
      int g2 = wvi;
      int br = cb + g2 * 16 + srow;
      size_t boff = (size_t)br * 256 + kt * 32 + schunk * 8;
      gl_lds16(Bt1h + boff, BhL + g2 * 512);
      gl_lds16(Bt1l + boff, BlL + g2 * 512);
    }
    __syncthreads();

    short8 ah[4], al[4];
    #pragma unroll
    for (int mt = 0; mt < 4; mt++) {
      int rg = wm * 4 + mt;
      ah[mt] = *(const short8*)&AhL[rg * 512 + quad * 128 + l15 * 8];
      al[mt] = *(const short8*)&AlL[rg * 512 + quad * 128 + l15 * 8];
    }
    #pragma unroll
    for (int nt = 0; nt < 2; nt++) {
      int rg = wn * 2 + nt;
      short8 bh = *(const short8*)&BhL[rg * 512 + quad * 128 + l15 * 8];
      short8 bl = *(const short8*)&BlL[rg * 512 + quad * 128 + l15 * 8];
      #pragma unroll
      for (int mt = 0; mt < 4; mt++) {
        acc[mt][nt] = __builtin_amdgcn_mfma_f32_16x16x32_bf16(ah[mt], bh, acc[mt][nt], 0, 0, 0);
        acc[mt][nt] = __builtin_amdgcn_mfma_f32_16x16x32_bf16(ah[mt], bl, acc[mt][nt], 0, 0, 0);
        acc[mt][nt] = __builtin_amdgcn_mfma_f32_16x16x32_bf16(al[mt], bh, acc[mt][nt], 0, 0, 0);
      }
    }
    __syncthreads();
  }

  if (ct < 8) {
    // fx: LDS transpose (64 cols x 128 rows), store fxT hi/lo
    short (*T)[136] = (short(*)[136])&smem[0];   // 64 x 136 shorts
    #pragma unroll
    for (int pass = 0; pass < 2; pass++) {
      __syncthreads();
      #pragma unroll
      for (int nt = 0; nt < 2; nt++) {
        int cl = wn * 32 + nt * 16 + l15;        // 0..63
        float bias = bfx[cb + cl];
        #pragma unroll
        for (int mt = 0; mt < 4; mt++) {
          short4 sv;
          #pragma unroll
          for (int r = 0; r < 4; r++) {
            float v = acc[mt][nt][r] + bias;
            short hi2 = f2bf(v);
            ((short*)&sv)[r] = pass ? f2bf(v - bf2f(hi2)) : hi2;
          }
          *(short4*)&T[cl][wm * 64 + mt * 16 + quad * 4] = sv;
        }
      }
      __syncthreads();
      short* dst = pass ? fxTl : fxTh;
      #pragma unroll
      for (int t = 0; t < 4; t++) {
        int idx2 = tid + t * 256;                 // 1024 int4 chunks
        int row = idx2 >> 4, kc = (idx2 & 15) * 8;
        *(int4*)&dst[(size_t)(cb + row) * NP + row0 + kc] = *(const int4*)&T[row][kc];
      }
    }
  } else {
    // w: logits -> tempered softmax; wave covers one 32-col group
    int ct2 = ct - 8;
    int lcb = ct2 * 64 + wn * 32;          // 32-aligned, 0..224
    int h = lcb >> 5;
    float inv_t = 1.0f / gtemp[h];
    int lc0 = lcb + l15, lc1 = lcb + 16 + l15;
    float b0 = bcomb[lc0], b1 = bcomb[lc1];
    #pragma unroll
    for (int mt = 0; mt < 4; mt++) {
      #pragma unroll
      for (int r = 0; r < 4; r++) {
        float s0 = (acc[mt][0][r] + b0) * inv_t;
        float s1 = (acc[mt][1][r] + b1) * inv_t;
        float m = fmaxf(s0, s1);
        #pragma unroll
        for (int off = 1; off < 16; off <<= 1) m = fmaxf(m, __shfl_xor(m, off, 16));
        float e0 = __expf(s0 - m), e1 = __expf(s1 - m);
        float sum = e0 + e1;
        #pragma unroll
        for (int off = 1; off < 16; off <<= 1) sum += __shfl_xor(sum, off, 16);
        float inv = 1.0f / sum;
        int row = row0 + wm * 64 + mt * 16 + quad * 4 + r;
        if (row < N) {
          float w0v = e0 * inv, w1v = e1 * inv;
          size_t base = (size_t)row * (NH * NS);
          short h0 = f2bf(w0v), h1 = f2bf(w1v);
          wh_out[base + lc0] = h0; wl_out[base + lc0] = f2bf(w0v - bf2f(h0));
          wh_out[base + lc1] = h1; wl_out[base + lc1] = f2bf(w1v - bf2f(h1));
        }
      }
    }
  }
}

// ---------------------------------------------------------------------------
// k_scat: slice_token[b,h,s,d] = sum_n w[n,hs]*fx[n,hd] (unchanged, verified).
// ---------------------------------------------------------------------------
__global__ __launch_bounds__(256) void k_scat(
    const short* __restrict__ wh, const short* __restrict__ wl,
    const short* __restrict__ fxTh, const short* __restrict__ fxTl,
    const int* __restrict__ seg,
    float* __restrict__ stok, float* __restrict__ snorm, int N)
{
  __shared__ short wth[32][136];
  __shared__ short wtl[32][136];
  __shared__ short fh[64][136];
  __shared__ short fl[64][136];
  __shared__ float ln[32];

  const int h = blockIdx.y;
  const int n0 = blockIdx.x * 512;
  const int tid = threadIdx.x;
  const int lane = tid & 63, l15 = lane & 15, quad = lane >> 4;
  const int wv = tid >> 6;
  const int nend = min(n0 + 512, N);

  f32x4 acc0 = (f32x4){0.f, 0.f, 0.f, 0.f};
  f32x4 acc1 = (f32x4){0.f, 0.f, 0.f, 0.f};

  for (int b = 0; b < NB; b++) {
    int lo = max(seg[b], n0), hi = min(seg[b + 1], nend);
    if (lo >= hi) continue;
    if (tid < 32) ln[tid] = 0.f;
    int c0lo = (lo - n0) & ~127;
    int c0hi = hi - n0;
    for (int c0 = c0lo; c0 < c0hi; c0 += 128) {
      __syncthreads();
      #pragma unroll
      for (int t = 0; t < 2; t++) {
        int idx2 = tid + t * 256;
        int row = idx2 >> 2;
        int sc  = (idx2 & 3) * 8;
        int ng = n0 + c0 + row;
        short8 vh = (short8){0,0,0,0,0,0,0,0};
        short8 vl = (short8){0,0,0,0,0,0,0,0};
        if (ng >= lo && ng < hi) {
          size_t src = (size_t)ng * 256 + h * 32 + sc;
          vh = *(const short8*)&wh[src];
          vl = *(const short8*)&wl[src];
        }
        #pragma unroll
        for (int j = 0; j < 8; j++) {
          wth[sc + j][row] = vh[j];
          wtl[sc + j][row] = vl[j];
        }
      }
      #pragma unroll
      for (int t = 0; t < 4; t++) {
        int idx2 = tid + t * 256;
        int row = idx2 >> 4, kc = (idx2 & 15) * 8;
        size_t src = (size_t)(h * 64 + row) * NP + n0 + c0 + kc;
        *(int4*)&fh[row][kc] = *(const int4*)&fxTh[src];
        *(int4*)&fl[row][kc] = *(const int4*)&fxTl[src];
      }
      __syncthreads();

      {
        int s = tid >> 3, g = tid & 7;
        float sum = 0.f;
        #pragma unroll
        for (int i2 = 0; i2 < 16; i2++) {
          int nl = g * 16 + i2;
          sum += bf2f(wth[s][nl]) + bf2f(wtl[s][nl]);
        }
        atomicAdd(&ln[s], sum);
      }

      for (int k0 = 0; k0 < 128; k0 += 32) {
        int gbase = n0 + c0 + k0;
        if (gbase + 32 <= lo || gbase >= hi) continue;
        short8 a0h = *(const short8*)&wth[l15][k0 + quad * 8];
        short8 a0l = *(const short8*)&wtl[l15][k0 + quad * 8];
        short8 a1h = *(const short8*)&wth[16 + l15][k0 + quad * 8];
        short8 a1l = *(const short8*)&wtl[16 + l15][k0 + quad * 8];
        short8 bh = *(const short8*)&fh[wv * 16 + l15][k0 + quad * 8];
        short8 bl = *(const short8*)&fl[wv * 16 + l15][k0 + quad * 8];
        acc0 = __builtin_amdgcn_mfma_f32_16x16x32_bf16(a0h, bh, acc0, 0, 0, 0);
        acc0 = __builtin_amdgcn_mfma_f32_16x16x32_bf16(a0h, bl, acc0, 0, 0, 0);
        acc0 = __builtin_amdgcn_mfma_f32_16x16x32_bf16(a0l, bh, acc0, 0, 0, 0);
        acc1 = __builtin_amdgcn_mfma_f32_16x16x32_bf16(a1h, bh, acc1, 0, 0, 0);
        acc1 = __builtin_amdgcn_mfma_f32_16x16x32_bf16(a1h, bl, acc1, 0, 0, 0);
        acc1 = __builtin_amdgcn_mfma_f32_16x16x32_bf16(a1l, bh, acc1, 0, 0, 0);
      }
    }
    __syncthreads();
    size_t base = ((size_t)b * NH + h) * NS;
    #pragma unroll
    for (int r = 0; r < 4; r++) {
      atomicAdd(&stok[(base + quad * 4 + r) * ND + wv * 16 + l15], acc0[r]);
      atomicAdd(&stok[(base + 16 + quad * 4 + r) * ND + wv * 16 + l15], acc1[r]);
    }
    if (tid < 32) atomicAdd(&snorm[base + tid], ln[tid]);
    acc0 = (f32x4){0.f, 0.f, 0.f, 0.f};
    acc1 = (f32x4){0.f, 0.f, 0.f, 0.f};
    __syncthreads();
  }
}

// ---------------------------------------------------------------------------
// k_attn: per (b,h) attention + P = out_tok @ Wout_h, store P^T bf16 hi/lo.
// ---------------------------------------------------------------------------
__global__ __launch_bounds__(256) void k_attn(
    const float* __restrict__ stok, const float* __restrict__ snorm,
    const float* __restrict__ Wq, const float* __restrict__ Wk,
    const float* __restrict__ Wv, const float* __restrict__ Wout,
    short* __restrict__ PTh, short* __restrict__ PTl)
{
  __shared__ float st[32][65];
  __shared__ float qs[32][65];
  __shared__ float ks[32][65];
  __shared__ float vs[32][65];
  __shared__ float at[32][33];
  __shared__ float ot[32][65];
  const int bh = blockIdx.x;
  const int b = bh >> 3, h = bh & 7;
  const int tid = threadIdx.x;

  for (int i = tid; i < 2048; i += 256) {
    int ss = i >> 6;
    float nrm = snorm[(size_t)bh * NS + ss] + 1e-5f;
    st[ss][i & 63] = stok[(size_t)bh * 2048 + i] / nrm;
  }
  __syncthreads();

  const int e = tid & 63, sgp = tid >> 6;
  for (int ii = 0; ii < 8; ii++) {
    int ss = sgp * 8 + ii;
    float aq = 0.f, ak = 0.f, av = 0.f;
    #pragma unroll 8
    for (int dd = 0; dd < 64; dd++) {
      float sv = st[ss][dd];
      aq += sv * Wq[dd * 64 + e];
      ak += sv * Wk[dd * 64 + e];
      av += sv * Wv[dd * 64 + e];
    }
    qs[ss][e] = aq; ks[ss][e] = ak; vs[ss][e] = av;
  }
  __syncthreads();

  const float scale = 0.125f;
  for (int i = tid; i < 1024; i += 256) {
    int si = i >> 5, tj = i & 31;
    float a = 0.f;
    #pragma unroll 8
    for (int ee = 0; ee < 64; ee++) a += qs[si][ee] * ks[tj][ee];
    at[si][tj] = a * scale;
  }
  __syncthreads();

  if (tid < 32) {
    float m = -1e30f;
    for (int j = 0; j < 32; j++) m = fmaxf(m, at[tid][j]);
    float sum = 0.f;
    for (int j = 0; j < 32; j++) { float ev = __expf(at[tid][j] - m); at[tid][j] = ev; sum += ev; }
    float inv = 1.f / sum;
    for (int j = 0; j < 32; j++) at[tid][j] *= inv;
  }
  __syncthreads();

  for (int ii = 0; ii < 8; ii++) {
    int ss = sgp * 8 + ii;
    float a = 0.f;
    #pragma unroll 8
    for (int tj = 0; tj < 32; tj++) a += at[ss][tj] * vs[tj][e];
    ot[ss][e] = a;
  }
  __syncthreads();

  const int s_p = tid >> 3;
  const int c0 = (tid & 7) * 32;
  float pacc[32];
  #pragma unroll
  for (int q = 0; q < 32; q++) pacc[q] = 0.f;
  for (int dd = 0; dd < 64; dd++) {
    float o = ot[s_p][dd];
    const float4* wr = (const float4*)&Wout[(size_t)(h * 64 + dd) * NDIM + c0];
    #pragma unroll
    for (int q = 0; q < 8; q++) {
      float4 v = wr[q];
      pacc[4 * q + 0] += o * v.x;
      pacc[4 * q + 1] += o * v.y;
      pacc[4 * q + 2] += o * v.z;
      pacc[4 * q + 3] += o * v.w;
    }
  }
  #pragma unroll
  for (int q = 0; q < 32; q++) {
    int c = c0 + q;
    float val = pacc[q];
    short hi = f2bf(val);
    size_t dst = ((size_t)b * NDIM + c) * 256 + h * 32 + s_p;
    PTh[dst] = hi;
    PTl[dst] = f2bf(val - bf2f(hi));
  }
}

// ---------------------------------------------------------------------------
// k_outw: out[n,c] = sum_{hs} w[n,hs] * PT[batch[n]][c][hs] + bout[c].
// 256 threads, BM=128 x BN=64, 4 ct tiles; acc[4][2]=32 AGPR.
// ---------------------------------------------------------------------------
__global__ __launch_bounds__(256) void k_outw(
    const short* __restrict__ wh, const short* __restrict__ wl,
    const short* __restrict__ PTh, const short* __restrict__ PTl,
    const int* __restrict__ batch, const float* __restrict__ bout,
    float* __restrict__ out, int N, int ntiles)
{
  __shared__ __align__(16) short smem[12288];
  short* AhL = &smem[0];
  short* AlL = &smem[4096];
  short* BhL = &smem[8192];
  short* BlL = &smem[10240];
  __shared__ int b_sh[128];

  const int lid = blockIdx.x;
  const int xcd = lid & 7;
  const int idx = lid >> 3;
  const int ct  = idx & 3;
  const int rowt = xcd + 8 * (idx >> 2);
  if (rowt >= ntiles) return;
  const int row0 = rowt * 128;
  const int tid = threadIdx.x;
  const int lane = tid & 63, l15 = lane & 15, quad = lane >> 4;
  const int wvi = tid >> 6, wm = wvi & 1, wn = wvi >> 1;
  const int cb = ct * 64;
  const int srow = lane & 15, schunk = lane >> 4;
  const int cnt = min(128, N - row0);

  if (tid < 128) b_sh[tid] = (tid < cnt) ? batch[row0 + tid] : -1;
  __syncthreads();

  f32x4 acc[4][2];
  #pragma unroll
  for (int i = 0; i < 4; i++)
    #pragma unroll
    for (int j = 0; j < 2; j++) acc[i][j] = (f32x4){0.f, 0.f, 0.f, 0.f};

  int i0 = 0;
  while (i0 < cnt) {
    int b = b_sh[i0];
    int j = i0;
    while (j < cnt && b_sh[j] == b) j++;
    const bool fullseg = (i0 == 0) && (j == cnt) && (cnt == 128);

    for (int kt = 0; kt < 8; kt++) {
      if (fullseg) {
        #pragma unroll
        for (int t = 0; t < 2; t++) {
          int g = wvi * 2 + t;
          int gr = row0 + g * 16 + srow;
          size_t aoff = (size_t)gr * 256 + kt * 32 + schunk * 8;
          gl_lds16(wh + aoff, AhL + g * 512);
          gl_lds16(wl + aoff, AlL + g * 512);
        }
      } else {
        #pragma unroll
        for (int t = 0; t < 2; t++) {
          int idx2 = tid + t * 256;              // 512 chunks
          int row = idx2 >> 2, kc8 = idx2 & 3;
          short8 vh = (short8){0,0,0,0,0,0,0,0};
          short8 vl = (short8){0,0,0,0,0,0,0,0};
          if (row >= i0 && row < j) {
            size_t src = (size_t)(row0 + row) * 256 + kt * 32 + kc8 * 8;
            vh = *(const short8*)&wh[src];
            vl = *(const short8*)&wl[src];
          }
          int dst = (row >> 4) * 512 + kc8 * 128 + (row & 15) * 8;
          *(short8*)&AhL[dst] = vh;
          *(short8*)&AlL[dst] = vl;
        }
      }
      {
        int g2 = wvi;
        int br = cb + g2 * 16 + srow;
        size_t boff = ((size_t)b * NDIM + br) * 256 + kt * 32 + schunk * 8;
        gl_lds16(PTh + boff, BhL + g2 * 512);
        gl_lds16(PTl + boff, BlL + g2 * 512);
      }
      __syncthreads();

      short8 ah[4], al[4];
      #pragma unroll
      for (int mt = 0; mt < 4; mt++) {
        int rg = wm * 4 + mt;
        ah[mt] = *(const short8*)&AhL[rg * 512 + quad * 128 + l15 * 8];
        al[mt] = *(const short8*)&AlL[rg * 512 + quad * 128 + l15 * 8];
      }
      #pragma unroll
      for (int nt = 0; nt < 2; nt++) {
        int rg = wn * 2 + nt;
        short8 bh = *(const short8*)&BhL[rg * 512 + quad * 128 + l15 * 8];
        short8 bl = *(const short8*)&BlL[rg * 512 + quad * 128 + l15 * 8];
        #pragma unroll
        for (int mt = 0; mt < 4; mt++) {
          acc[mt][nt] = __builtin_amdgcn_mfma_f32_16x16x32_bf16(ah[mt], bh, acc[mt][nt], 0, 0, 0);
          acc[mt][nt] = __builtin_amdgcn_mfma_f32_16x16x32_bf16(ah[mt], bl, acc[mt][nt], 0, 0, 0);
          acc[mt][nt] = __builtin_amdgcn_mfma_f32_16x16x32_bf16(al[mt], bh, acc[mt][nt], 0, 0, 0);
        }
      }
      __syncthreads();
    }
    i0 = j;
  }

  #pragma unroll
  for (int nt = 0; nt < 2; nt++) {
    int c = cb + wn * 32 + nt * 16 + l15;
    float bias = bout[c];
    #pragma unroll
    for (int mt = 0; mt < 4; mt++)
      #pragma unroll
      for (int r = 0; r < 4; r++) {
        int row = row0 + wm * 64 + mt * 16 + quad * 4 + r;
        if (row < N) out[(size_t)row * NDIM + c] = acc[mt][nt][r] + bias;
      }
  }
}

// ---------------------------------------------------------------------------
extern "C" void kernel_launch(void* const* d_in, const int* in_sizes, int n_in,
                              void* d_out, int out_size, void* d_ws, size_t ws_size,
                              hipStream_t stream) {
  const float* x      = (const float*)d_in[0];
  const int*   batch  = (const int*)d_in[1];
  const float* Wfx    = (const float*)d_in[2];
  const float* bfx    = (const float*)d_in[3];
  const float* Wx     = (const float*)d_in[4];
  const float* bx     = (const float*)d_in[5];
  const float* Wsl    = (const float*)d_in[6];
  const float* bsl    = (const float*)d_in[7];
  const float* gtemp  = (const float*)d_in[8];
  const float* Wq     = (const float*)d_in[9];
  const float* Wk     = (const float*)d_in[10];
  const float* Wv     = (const float*)d_in[11];
  const float* Wout   = (const float*)d_in[12];
  const float* bout   = (const float*)d_in[13];
  float* out = (float*)d_out;

  const int N = in_sizes[0] / NDIM;   // 30000

  float* stok  = (float*)d_ws;                     // 131072
  float* snorm = stok + 131072;                    // 2048
  float* bcomb = snorm + 2048;                     // 256
  int*   seg   = (int*)(bcomb + 256);              // 16
  short* Bt1h  = (short*)(seg + 16);               // 196608
  short* Bt1l  = Bt1h + 196608;
  short* Xh    = Bt1l + 196608;                    // N*256
  short* Xl    = Xh + 7680000;
  short* whb   = Xl + 7680000;                     // NP*256
  short* wlb   = whb + (size_t)NP * 256;
  short* fxTh  = wlb + (size_t)NP * 256;           // 512*NP
  short* fxTl  = fxTh + (size_t)512 * NP;
  short* PTh   = fxTl + (size_t)512 * NP;          // 524288
  short* PTl   = PTh + 524288;

  hipMemsetAsync(stok, 0, (size_t)(131072 + 2048) * sizeof(float), stream);
  hipMemsetAsync(seg, 0x7f, 16 * sizeof(int), stream);

  const int xs_blocks = (N * 64 + 255) / 256;      // 7500
  k_pre<<<xs_blocks + 770 + (N + 255) / 256, 256, 0, stream>>>(
      x, Xh, Xl, Wfx, Wx, bx, Wsl, bsl, Bt1h, Bt1l, bcomb, batch, seg, N);

  const int ntiles = (N + 127) / 128;              // 235
  const int qmax = (ntiles + 7) / 8;               // 30
  k_fxw<<<8 * qmax * 12, 256, 0, stream>>>(Xh, Xl, Bt1h, Bt1l, bfx, bcomb, gtemp,
                                           fxTh, fxTl, whb, wlb, N, ntiles);

  dim3 g2((N + 511) / 512, NH);
  k_scat<<<g2, 256, 0, stream>>>(whb, wlb, fxTh, fxTl, seg, stok, snorm, N);

  k_attn<<<NB * NH, 256, 0, stream>>>(stok, snorm, Wq, Wk, Wv, Wout, PTh, PTl);

  k_outw<<<8 * qmax * 4, 256, 0, stream>>>(whb, wlb, PTh, PTl, batch, bout, out, N, ntiles);
}